// Round 10
// baseline (1766.045 us; speedup 1.0000x reference)
//
#include <hip/hip_runtime.h>
#include <hip/hip_bf16.h>

// Problem dims
#define BB   256
#define TIN  336
#define TOUT 96
#define FF   32
#define HH   256

#define NGS 16   // gate-column slices (gi)
#define NBG 16   // batch groups (gb)
#define RPG 16   // batch rows per group
#define TPB 512

#define KB0 9        // enc L0: K=288 = [x(32) | h0(256)]
#define KB1 16       // K=512 phases
#define AST 260      // AH0/AH1 row stride (bf16): 520B, +2-mod-32 bank walk
#define XST 40       // X-tile row stride (bf16)

// ws layout in ushort units
#define N_L0  (16*4*KB0*64*8)      // 294912 (enc L0, K=288)
#define N_L1  (16*4*KB1*64*8)      // 524288 (K=512 regions)
#define U_E0  0
#define U_E1  (U_E0 + N_L0)        // enc L1
#define U_D0  (U_E1 + N_L1)        // dec L0' = [Whh0 | W_eff], K=512
#define U_D1  (U_D0 + N_L1)        // dec L1
#define U_END (U_D1 + N_L1)        // 1867776
#define HPAR  65536                // one parity buffer: 256x256 bf16
#define U_H0  U_END                // h0 parity x2
#define U_H1  (U_H0 + 2*HPAR)      // enc h1 parity x2
#define U_HD  (U_H1 + 2*HPAR)      // dec h1 parity x2 (y computed in-loop from LDS)
#define U_CTR (U_HD + 2*HPAR)      // flags: [gb][3 x 32 dwords] = A,B,D lines
#define U_ZEND (U_CTR + 4096)

// gate accumulate from doubled pbuf (phase L)
#define GATE(L, bias, g, r, cc) (bias[(g)*16 + (cc)] + pbuf[L][0][r][(g)*16 + (cc)] + pbuf[L][1][r][(g)*16 + (cc)])

typedef __bf16 bf16x8 __attribute__((ext_vector_type(8)));
typedef float  f32x4  __attribute__((ext_vector_type(4)));

__device__ __forceinline__ float sigf(float x) { return 1.f / (1.f + __expf(-x)); }
__device__ __forceinline__ float tanhfast(float x) { return 1.f - 2.f / (__expf(2.f * x) + 1.f); }
__device__ __forceinline__ unsigned short f2bf(float f) {   // RNE bf16
    union { float f; unsigned u; } v; v.f = f;
    unsigned r = v.u + 0x7FFF + ((v.u >> 16) & 1);
    return (unsigned short)(r >> 16);
}
// coherence-point loads (bypass L1+L2): pair with write-through producer stores
__device__ __forceinline__ uint4 ldg_sc(const void* p) {
    uint4 v;
    asm volatile("global_load_dwordx4 %0, %1, off sc0 sc1\n\ts_waitcnt vmcnt(0)"
                 : "=v"(v) : "v"(p) : "memory");
    return v;
}
__device__ __forceinline__ void ldg_sc2(const void* p0, const void* p1, uint4& a, uint4& b) {
    asm volatile("global_load_dwordx4 %0, %2, off sc0 sc1\n\t"
                 "global_load_dwordx4 %1, %3, off sc0 sc1\n\t"
                 "s_waitcnt vmcnt(0)"
                 : "=v"(a), "=v"(b) : "v"(p0), "v"(p1) : "memory");
}

// ---- prep: bf16 MFMA-fragment weight slices (enc L0/L1, dec [Whh0|W_eff], dec L1) ----
__global__ void prep_kernel(const float* __restrict__ eWih0, const float* __restrict__ eWhh0,
                            const float* __restrict__ eWih1, const float* __restrict__ eWhh1,
                            const float* __restrict__ dWih0, const float* __restrict__ dWhh0,
                            const float* __restrict__ dWih1, const float* __restrict__ dWhh1,
                            const float* __restrict__ Wout,  float* __restrict__ wsf)
{
    unsigned short* wsu = (unsigned short*)wsf;
    for (long u = (long)blockIdx.x * blockDim.x + threadIdx.x; u < (long)U_END;
         u += (long)gridDim.x * blockDim.x) {
        int region; long l;
        if (u < U_E1)      { region = 0; l = u - U_E0; }
        else if (u < U_D0) { region = 1; l = u - U_E1; }
        else if (u < U_D1) { region = 2; l = u - U_D0; }
        else               { region = 3; l = u - U_D1; }
        const int KB = (region == 0) ? KB0 : KB1;
        int j = (int)(l & 7), lane = (int)((l >> 3) & 63);
        long rem = l >> 9;
        int kb = (int)(rem % KB), q = (int)(rem / KB);
        int nt = q & 3, gi = q >> 2;
        int k  = kb * 32 + ((lane >> 4) << 3) + j;
        int gj = nt * 256 + gi * 16 + (lane & 15);
        float v;
        if (region == 0)      v = (k < 32)  ? eWih0[gj * 32 + k]  : eWhh0[gj * 256 + (k - 32)];
        else if (region == 1) v = (k < 256) ? eWih1[gj * 256 + k] : eWhh1[gj * 256 + (k - 256)];
        else if (region == 2) {
            if (k < 256) v = dWhh0[gj * 256 + k];
            else {                               // W_eff = dWih0 . Wout
                float acc = 0.f; int kk = k - 256;
                #pragma unroll 8
                for (int f = 0; f < 32; ++f) acc += dWih0[gj * 32 + f] * Wout[f * 256 + kk];
                v = acc;
            }
        } else                v = (k < 256) ? dWih1[gj * 256 + k] : dWhh1[gj * 256 + (k - 256)];
        wsu[u] = f2bf(v);
    }
    // zero h0/h1 parity buffers (h(-1)=0, h1(-1)=0) + flags
    for (long z = (long)blockIdx.x * blockDim.x + threadIdx.x; z < (long)(4 * HPAR);
         z += (long)gridDim.x * blockDim.x)
        wsu[U_H0 + z] = 0;
    for (long z = (long)blockIdx.x * blockDim.x + threadIdx.x; z < 4096;
         z += (long)gridDim.x * blockDim.x)
        wsu[U_CTR + z] = 0;
}

// ---- persistent seq2seq: 256 wgs = 16 batch-groups x 16 gate-slices ----
// Encoder: FUSED iteration. B0(s)+B1(s-1) MFMA back-to-back (doubled pbuf);
// wave0 = all h0 cell slots -> drain -> post flagA(s+1); wave1 = all h1 slots
// -> drain -> post flagB(s+1) (each wave certifies ONLY its own stores, so the
// posts are barrier-free => no circular wait); wave7 polls the 15 PEER flags
// concurrently (own stores certified by program order + closing barrier).
// One exchange per step stages h0(s)+h1(s-1). Decoder: R8-proven structure on
// a separate flagD counter.
__global__ __launch_bounds__(TPB) void lstm_main(
    const float* __restrict__ x,
    const float* __restrict__ eb0, const float* __restrict__ eb1,
    const float* __restrict__ db0, const float* __restrict__ db1,
    const float* __restrict__ Wout, const float* __restrict__ bout,
    const float* __restrict__ dWih0,
    float* __restrict__ ws, float* __restrict__ out)
{
    const int gi = blockIdx.x >> 4;
    const int gb = blockIdx.x & 15;   // stride-16 blocks -> same XCD per group

    unsigned short* wsu = (unsigned short*)ws;
    const unsigned short* h0u = wsu + U_H0;
    const unsigned short* h1u = wsu + U_H1;
    const unsigned short* hdu = wsu + U_HD;
    unsigned* h0d = (unsigned*)(wsu + U_H0);
    unsigned* h1d = (unsigned*)(wsu + U_H1);
    unsigned* hdd = (unsigned*)(wsu + U_HD);
    unsigned* flgA = (unsigned*)(wsu + U_CTR) + gb * 96;
    unsigned* flgB = flgA + 32;
    unsigned* flgD = flgA + 64;

    const int t  = threadIdx.x;
    const int wv = t >> 6;
    const int ln = t & 63;
    const int nt = wv & 3, w2 = wv >> 2;
    const int arow = ln & 15, ak = (ln >> 4) << 3;

    __shared__ __align__(16) unsigned short AH0[16 * AST];   // h0 tile (8.1 KB)
    __shared__ __align__(16) unsigned short AH1[16 * AST];   // h1/hd tile
    __shared__ __align__(16) unsigned short Xt[16 * XST];
    __shared__ float pbuf[2][2][16][68];                     // [phase][w2]
    __shared__ float cst[2][16][16];
    __shared__ float sb[5][64];   // eb0, eb1, b_eff, db1, db0

    if (t < 64) {
        int gj = (t >> 4) * 256 + gi * 16 + (t & 15);
        sb[0][t] = eb0[gj]; sb[1][t] = eb1[gj]; sb[3][t] = db1[gj]; sb[4][t] = db0[gj];
        float be = db0[gj];
        #pragma unroll 8
        for (int f = 0; f < 32; ++f) be += dWih0[gj * 32 + f] * bout[f];
        sb[2][t] = be;
    }
    if (t < 256) { cst[0][t >> 4][t & 15] = 0.f; cst[1][t >> 4][t & 15] = 0.f; }

    // per-wave register-resident B fragments
    bf16x8 B0[8], B1[8];
    const int kbs0 = w2 ? 4 : 0, kbn0 = w2 ? 5 : 4;   // enc L0 split of KB0=9
    const int kbs1 = w2 ? 8 : 0;                       // K=512 split: 8 each
    auto loadB = [&](size_t ubase, int KB, int kbs, int kbn, bf16x8* Breg) {
        #pragma unroll
        for (int i = 0; i < 8; ++i)
            if (i < kbn)
                Breg[i] = *(const bf16x8*)(wsu + ubase +
                            ((size_t)(nt * KB + kbs + i) * 64 + ln) * 8);
    };

    // MFMA blocks -> pbuf[ph]
    auto mfmaB0 = [&]() {   // enc L0: kb0 = Xt, kb>=1 -> AH0
        f32x4 acc = {0.f, 0.f, 0.f, 0.f};
        #pragma unroll
        for (int i = 0; i < 8; ++i) {
            if (i < kbn0) {
                const int kb = kbs0 + i;
                bf16x8 a;
                if (kb == 0) a = *(const bf16x8*)(Xt + arow * XST + ak);
                else         a = *(const bf16x8*)(AH0 + arow * AST + (kb - 1) * 32 + ak);
                acc = __builtin_amdgcn_mfma_f32_16x16x32_bf16(a, B0[i], acc, 0, 0, 0);
            }
        }
        #pragma unroll
        for (int rg = 0; rg < 4; ++rg)
            pbuf[0][w2][(ln >> 4) * 4 + rg][nt * 16 + arow] = acc[rg];
    };
    auto mfmaK512 = [&](const bf16x8* Breg, int ph) {   // kb<8 -> AH0, kb>=8 -> AH1
        f32x4 acc = {0.f, 0.f, 0.f, 0.f};
        #pragma unroll
        for (int i = 0; i < 8; ++i) {
            const int kb = kbs1 + i;
            bf16x8 a;
            if (kb < 8) a = *(const bf16x8*)(AH0 + arow * AST + kb * 32 + ak);
            else        a = *(const bf16x8*)(AH1 + arow * AST + (kb - 8) * 32 + ak);
            acc = __builtin_amdgcn_mfma_f32_16x16x32_bf16(a, Breg[i], acc, 0, 0, 0);
        }
        #pragma unroll
        for (int rg = 0; rg < 4; ++rg)
            pbuf[ph][w2][(ln >> 4) * 4 + rg][nt * 16 + arow] = acc[rg];
    };

    // one cell slot q (r=q>>3, c2=q&7) of layer-phase L -> write-through store
    auto cellSlot = [&](int L, int q, const float* bias, unsigned* dstDw) {
        const int r = q >> 3, c2 = q & 7;
        const int c0 = c2 * 2, c1 = c0 + 1;
        float xi0 = GATE(L, bias, 0, r, c0), xf0 = GATE(L, bias, 1, r, c0);
        float xg0 = GATE(L, bias, 2, r, c0), xo0 = GATE(L, bias, 3, r, c0);
        float xi1 = GATE(L, bias, 0, r, c1), xf1 = GATE(L, bias, 1, r, c1);
        float xg1 = GATE(L, bias, 2, r, c1), xo1 = GATE(L, bias, 3, r, c1);
        float ca = cst[L][r][c0], cb = cst[L][r][c1];
        float cn0 = sigf(xf0) * ca + sigf(xi0) * tanhfast(xg0);
        float cn1 = sigf(xf1) * cb + sigf(xi1) * tanhfast(xg1);
        cst[L][r][c0] = cn0; cst[L][r][c1] = cn1;
        float h0v = sigf(xo0) * tanhfast(cn0);
        float h1v = sigf(xo1) * tanhfast(cn1);
        unsigned pv = (unsigned)f2bf(h0v) | ((unsigned)f2bf(h1v) << 16);
        __hip_atomic_store(dstDw + (size_t)(gb * RPG + r) * 128 + gi * 8 + c2, pv,
                           __ATOMIC_RELAXED, __HIP_MEMORY_SCOPE_AGENT);
    };

    // wave7 peer-poll precomputed address/exemption (lanes 0..15 -> flagA peers,
    // 16..31 -> flagB peers, others exempt)
    const unsigned* ppoll;
    bool pexempt;
    if (ln < 16)      { ppoll = flgA + ln;        pexempt = (ln == gi); }
    else if (ln < 32) { ppoll = flgB + (ln - 16); pexempt = ((ln - 16) == gi); }
    else              { ppoll = flgA + gi;        pexempt = true; }

    // ---- init: enc B-fragments; AH0 = h0(-1) = 0; Xt = x(0) ----
    loadB(U_E0 + (size_t)gi * 18432, KB0, kbs0, kbn0, B0);
    loadB(U_E1 + (size_t)gi * 32768, KB1, kbs1, 8,    B1);
    { const int r = t >> 5, c8 = t & 31;
      uint4 z = {0u, 0u, 0u, 0u};
      *(uint4*)(AH0 + r * AST + c8 * 8) = z;
      Xt[r * XST + c8] = f2bf(x[((size_t)(gb * RPG + r) * TIN) * FF + c8]); }
    __syncthreads();

    // ---- encoder: fused B0(s)+B1(s-1), 1 exchange/step ----
    for (int s = 0; s < TIN; ++s) {
        // A: MFMAs + x prefetch
        mfmaB0();
        if (s > 0) mfmaK512(B1, 1);
        const int r5 = t >> 5, c85 = t & 31;
        const int xs = (s + 1 < TIN) ? s + 1 : -1;
        float xv = 0.f;
        if (xs >= 0) xv = x[((size_t)(gb * RPG + r5) * TIN + xs) * FF + c85];
        __syncthreads();                                   // B
        // C: parallel cells + posts + peer poll
        if (wv == 0) {
            cellSlot(0, ln,      sb[0], h0d + (size_t)(s & 1) * (HPAR / 2));
            cellSlot(0, ln + 64, sb[0], h0d + (size_t)(s & 1) * (HPAR / 2));
            asm volatile("s_waitcnt vmcnt(0)" ::: "memory");
            if (ln == 0)
                __hip_atomic_store(flgA + gi, (unsigned)(s + 1), __ATOMIC_RELAXED,
                                   __HIP_MEMORY_SCOPE_AGENT);
        } else if (wv == 1) {
            if (s > 0) {
                cellSlot(1, ln,      sb[1], h1d + (size_t)((s - 1) & 1) * (HPAR / 2));
                cellSlot(1, ln + 64, sb[1], h1d + (size_t)((s - 1) & 1) * (HPAR / 2));
            }
            asm volatile("s_waitcnt vmcnt(0)" ::: "memory");
            if (ln == 0)
                __hip_atomic_store(flgB + gi, (unsigned)(s + 1), __ATOMIC_RELAXED,
                                   __HIP_MEMORY_SCOPE_AGENT);
        } else if (wv == 7) {
            const unsigned tgt = (unsigned)(s + 1);
            for (;;) {
                unsigned v = __hip_atomic_load(ppoll, __ATOMIC_RELAXED,
                                               __HIP_MEMORY_SCOPE_AGENT);
                if (__all((int)(pexempt || v >= tgt))) break;
                __builtin_amdgcn_s_sleep(1);
            }
        }
        __syncthreads();                                   // E
        // stage h0(s) + h1(s-1); write Xt
        {
            uint4 a, b;
            ldg_sc2(h0u + (size_t)(s & 1) * HPAR + (size_t)(gb * RPG + r5) * 256 + c85 * 8,
                    h1u + (size_t)((s - 1) & 1) * HPAR + (size_t)(gb * RPG + r5) * 256 + c85 * 8,
                    a, b);
            *(uint4*)(AH0 + r5 * AST + c85 * 8) = a;
            *(uint4*)(AH1 + r5 * AST + c85 * 8) = b;
            if (xs >= 0) Xt[r5 * XST + c85] = f2bf(xv);
        }
        __syncthreads();                                   // F
    }

    // ---- encoder tail: B1(TIN-1) (AH0=h0(335), AH1=h1(334)) ----
    {
        mfmaK512(B1, 1);
        __syncthreads();
        if (t < 128)
            cellSlot(1, t, sb[1], h1d + (size_t)((TIN - 1) & 1) * (HPAR / 2));
        asm volatile("s_waitcnt vmcnt(0)" ::: "memory");
        __syncthreads();
    }

    // ---- decoder B-fragments + Wout slice ----
    loadB(U_D0 + (size_t)gi * 32768, KB1, kbs1, 8, B0);
    loadB(U_D1 + (size_t)gi * 32768, KB1, kbs1, 8, B1);
    const int yr = t >> 5, yfq = (t >> 4) & 1, ykc = t & 15;
    const int yf = gi * 2 + yfq;
    float wreg[16];
    #pragma unroll
    for (int i = 0; i < 16; ++i) wreg[i] = Wout[(size_t)yf * 256 + ykc * 16 + i];
    const float ybo = bout[yf];
    auto ycompute = [&](int td) {
        const unsigned* ap = (const unsigned*)(AH1 + yr * AST + ykc * 16);
        float a = 0.f;
        #pragma unroll
        for (int j = 0; j < 8; ++j) {
            unsigned w = ap[j];
            a = fmaf(__uint_as_float(w << 16),         wreg[2 * j],     a);
            a = fmaf(__uint_as_float(w & 0xffff0000u), wreg[2 * j + 1], a);
        }
        #pragma unroll
        for (int off = 1; off < 16; off <<= 1) a += __shfl_xor(a, off, 64);
        if (ykc == 0)
            out[((size_t)(gb * RPG + yr) * TOUT + td) * FF + yf] = a + ybo;
    };

    int postsD = 0;
    auto gsyncD = [&]() {   // R8-proven: post + wave0 full poll + barrier
        ++postsD;
        if (t == 0)
            __hip_atomic_store(flgD + gi, (unsigned)postsD, __ATOMIC_RELAXED,
                               __HIP_MEMORY_SCOPE_AGENT);
        if (wv == 0) {
            for (;;) {
                unsigned v = __hip_atomic_load(flgD + (ln & 15), __ATOMIC_RELAXED,
                                               __HIP_MEMORY_SCOPE_AGENT);
                if (__all((int)(v >= (unsigned)postsD))) break;
                __builtin_amdgcn_s_sleep(1);
            }
        }
        __syncthreads();
    };

    // decoder MFMA phase (R8 structure, AH0/AH1 mapping, pbuf[0])
    auto phaseD = [&](const bf16x8* Breg, const float* bias, int layer,
                      unsigned* hdstDw, bool addY0) {
        mfmaK512(Breg, 0);
        __syncthreads();
        if (t < 128) {
            const int r = t >> 3, c2 = t & 7;
            const int c0 = c2 * 2, c1 = c0 + 1;
            float xi0 = GATE(0, bias, 0, r, c0), xf0 = GATE(0, bias, 1, r, c0);
            float xg0 = GATE(0, bias, 2, r, c0), xo0 = GATE(0, bias, 3, r, c0);
            float xi1 = GATE(0, bias, 0, r, c1), xf1 = GATE(0, bias, 1, r, c1);
            float xg1 = GATE(0, bias, 2, r, c1), xo1 = GATE(0, bias, 3, r, c1);
            if (addY0) {                       // first dec step: + Wih0 * y0
                const float* xp = x + ((size_t)(gb * RPG + r) * TIN + (TIN - 1)) * FF;
                float xr[32];
                #pragma unroll
                for (int f = 0; f < 32; ++f) xr[f] = xp[f];
                #pragma unroll
                for (int g = 0; g < 4; ++g) {
                    const float* w0 = dWih0 + (size_t)(g * 256 + gi * 16 + c0) * 32;
                    const float* w1 = dWih0 + (size_t)(g * 256 + gi * 16 + c1) * 32;
                    float a0 = 0.f, a1 = 0.f;
                    #pragma unroll
                    for (int f = 0; f < 32; ++f) {
                        a0 = fmaf(w0[f], xr[f], a0);
                        a1 = fmaf(w1[f], xr[f], a1);
                    }
                    if (g == 0) { xi0 += a0; xi1 += a1; }
                    else if (g == 1) { xf0 += a0; xf1 += a1; }
                    else if (g == 2) { xg0 += a0; xg1 += a1; }
                    else { xo0 += a0; xo1 += a1; }
                }
            }
            float ca = cst[layer][r][c0], cb = cst[layer][r][c1];
            float cn0 = sigf(xf0) * ca + sigf(xi0) * tanhfast(xg0);
            float cn1 = sigf(xf1) * cb + sigf(xi1) * tanhfast(xg1);
            cst[layer][r][c0] = cn0; cst[layer][r][c1] = cn1;
            float h0v = sigf(xo0) * tanhfast(cn0);
            float h1v = sigf(xo1) * tanhfast(cn1);
            unsigned pv = (unsigned)f2bf(h0v) | ((unsigned)f2bf(h1v) << 16);
            __hip_atomic_store(hdstDw + (size_t)(gb * RPG + r) * 128 + gi * 8 + c2, pv,
                               __ATOMIC_RELAXED, __HIP_MEMORY_SCOPE_AGENT);
        }
        asm volatile("s_waitcnt vmcnt(0)" : : : "memory");
        __syncthreads();
    };

    // ---- decoder: h0 persists in AH0; hd/h1 in AH1 ----
    for (int td = 0; td < TOUT; ++td) {
        const int s = TIN + td;
        const int wp = (s & 1) ^ 1;
        gsyncD();                                  // td=0: certifies tail h1(335)
        {
            const int r = t >> 5, c8 = t & 31;
            if (td == 0) {
                uint4 z = {0u, 0u, 0u, 0u};
                *(uint4*)(AH1 + r * AST + c8 * 8) = z;     // W_eff*0; y0 via addY0
            } else {
                uint4 a = ldg_sc(hdu + (size_t)((td - 1) & 1) * HPAR +
                                 (size_t)(gb * RPG + r) * 256 + c8 * 8);
                *(uint4*)(AH1 + r * AST + c8 * 8) = a;
            }
            __syncthreads();
        }
        if (td > 0) ycompute(td - 1);
        phaseD(B0, (td == 0) ? sb[4] : sb[2], 0,
               h0d + (size_t)wp * (HPAR / 2), td == 0);
        gsyncD();                                  // publishes h0(s)
        {
            const int r = t >> 5, c8 = t & 31;
            if (td == 0) {
                uint4 a, b;
                ldg_sc2(h0u + (size_t)wp * HPAR + (size_t)(gb * RPG + r) * 256 + c8 * 8,
                        h1u + (size_t)((TIN - 1) & 1) * HPAR /* h1(335) */ +
                            (size_t)(gb * RPG + r) * 256 + c8 * 8, a, b);
                *(uint4*)(AH0 + r * AST + c8 * 8) = a;
                *(uint4*)(AH1 + r * AST + c8 * 8) = b;
            } else {
                uint4 a = ldg_sc(h0u + (size_t)wp * HPAR +
                                 (size_t)(gb * RPG + r) * 256 + c8 * 8);
                *(uint4*)(AH0 + r * AST + c8 * 8) = a;
            }
            __syncthreads();
        }
        phaseD(B1, sb[3], 1, hdd + (size_t)(td & 1) * (HPAR / 2), false);
    }

    // ---- final sync: publishes hd(TOUT-1); then y(TOUT-1) ----
    gsyncD();
    {
        const int r = t >> 5, c8 = t & 31;
        uint4 a = ldg_sc(hdu + (size_t)((TOUT - 1) & 1) * HPAR +
                         (size_t)(gb * RPG + r) * 256 + c8 * 8);
        *(uint4*)(AH1 + r * AST + c8 * 8) = a;
        __syncthreads();
    }
    ycompute(TOUT - 1);
}

extern "C" void kernel_launch(void* const* d_in, const int* in_sizes, int n_in,
                              void* d_out, int out_size, void* d_ws, size_t ws_size,
                              hipStream_t stream) {
    const float* x     = (const float*)d_in[0];
    const float* eWih0 = (const float*)d_in[1];
    const float* eWhh0 = (const float*)d_in[2];
    const float* eb0   = (const float*)d_in[3];
    const float* eWih1 = (const float*)d_in[4];
    const float* eWhh1 = (const float*)d_in[5];
    const float* eb1   = (const float*)d_in[6];
    const float* dWih0 = (const float*)d_in[7];
    const float* dWhh0 = (const float*)d_in[8];
    const float* db0   = (const float*)d_in[9];
    const float* dWih1 = (const float*)d_in[10];
    const float* dWhh1 = (const float*)d_in[11];
    const float* db1   = (const float*)d_in[12];
    const float* dWout = (const float*)d_in[13];
    const float* dbout = (const float*)d_in[14];
    float* ws = (float*)d_ws;
    float* out = (float*)d_out;

    prep_kernel<<<1024, 256, 0, stream>>>(eWih0, eWhh0, eWih1, eWhh1,
                                          dWih0, dWhh0, dWih1, dWhh1, dWout, ws);
    lstm_main<<<NGS * NBG, TPB, 0, stream>>>(x, eb0, eb1, db0, db1,
                                             dWout, dbout, dWih0, ws, out);
}

// Round 11
// 1495.876 us; speedup vs baseline: 1.1806x; 1.1806x over previous
//
#include <hip/hip_runtime.h>
#include <hip/hip_bf16.h>

// Problem dims
#define BB   256
#define TIN  336
#define TOUT 96
#define FF   32
#define HH   256

#define NGS 16   // gate-column slices (gi)
#define NBG 16   // batch groups (gb)
#define RPG 16   // batch rows per group
#define TPB 512

#define KB0 9        // enc L0: K=288 = [x(32) | h0(256)]
#define KB1 16       // K=512 phases
#define ASTRIDE 520  // A-tile row stride (bf16)
#define XSTRIDE 40   // X-tile row stride (bf16)

// ws layout in ushort units
#define N_L0  (16*4*KB0*64*8)      // 294912 (enc L0, K=288)
#define N_L1  (16*4*KB1*64*8)      // 524288 (K=512 regions)
#define U_E0  0
#define U_E1  (U_E0 + N_L0)        // enc L1
#define U_D0  (U_E1 + N_L1)        // dec L0' = [Whh0 | W_eff], K=512
#define U_D1  (U_D0 + N_L1)        // dec L1
#define U_END (U_D1 + N_L1)        // 1867776
#define HPAR  65536                // one parity buffer: 256x256 bf16
#define U_H0  U_END                // h0 parity x2
#define U_H1  (U_H0 + 2*HPAR)      // h1 parity x2 (encoder)
#define U_HD  (U_H1 + 2*HPAR)      // decoder h1 per-step buffers x96
#define U_CTR (U_HD + 96*HPAR)     // flags: [gb][32 uints]
#define U_ZEND (U_CTR + 2048)

#define GATE(bias, g, r, cc) (bias[(g)*16 + (cc)] + pbuf[0][r][(g)*16 + (cc)] + pbuf[1][r][(g)*16 + (cc)])

typedef __bf16 bf16x8 __attribute__((ext_vector_type(8)));
typedef float  f32x4  __attribute__((ext_vector_type(4)));

__device__ __forceinline__ float sigf(float x) { return 1.f / (1.f + __expf(-x)); }
__device__ __forceinline__ float tanhfast(float x) { return 1.f - 2.f / (__expf(2.f * x) + 1.f); }
__device__ __forceinline__ unsigned short f2bf(float f) {   // RNE bf16
    union { float f; unsigned u; } v; v.f = f;
    unsigned r = v.u + 0x7FFF + ((v.u >> 16) & 1);
    return (unsigned short)(r >> 16);
}
// coherence-point loads (bypass L1+L2): pair with write-through producer stores
__device__ __forceinline__ uint4 ldg_sc(const void* p) {
    uint4 v;
    asm volatile("global_load_dwordx4 %0, %1, off sc0 sc1\n\ts_waitcnt vmcnt(0)"
                 : "=v"(v) : "v"(p) : "memory");
    return v;
}
__device__ __forceinline__ void ldg_sc2(const void* p0, const void* p1, uint4& a, uint4& b) {
    asm volatile("global_load_dwordx4 %0, %2, off sc0 sc1\n\t"
                 "global_load_dwordx4 %1, %3, off sc0 sc1\n\t"
                 "s_waitcnt vmcnt(0)"
                 : "=v"(a), "=v"(b) : "v"(p0), "v"(p1) : "memory");
}

// ---- prep: bf16 MFMA-fragment weight slices (enc L0/L1, dec [Whh0 | W_eff], dec L1) ----
__global__ void prep_kernel(const float* __restrict__ eWih0, const float* __restrict__ eWhh0,
                            const float* __restrict__ eWih1, const float* __restrict__ eWhh1,
                            const float* __restrict__ dWih0, const float* __restrict__ dWhh0,
                            const float* __restrict__ dWih1, const float* __restrict__ dWhh1,
                            const float* __restrict__ Wout,  float* __restrict__ wsf)
{
    unsigned short* wsu = (unsigned short*)wsf;
    for (long u = (long)blockIdx.x * blockDim.x + threadIdx.x; u < (long)U_END;
         u += (long)gridDim.x * blockDim.x) {
        int region; long l;
        if (u < U_E1)      { region = 0; l = u - U_E0; }
        else if (u < U_D0) { region = 1; l = u - U_E1; }
        else if (u < U_D1) { region = 2; l = u - U_D0; }
        else               { region = 3; l = u - U_D1; }
        const int KB = (region == 0) ? KB0 : KB1;
        int j = (int)(l & 7), lane = (int)((l >> 3) & 63);
        long rem = l >> 9;
        int kb = (int)(rem % KB), q = (int)(rem / KB);
        int nt = q & 3, gi = q >> 2;
        int k  = kb * 32 + ((lane >> 4) << 3) + j;
        int gj = nt * 256 + gi * 16 + (lane & 15);
        float v;
        if (region == 0)      v = (k < 32)  ? eWih0[gj * 32 + k]  : eWhh0[gj * 256 + (k - 32)];
        else if (region == 1) v = (k < 256) ? eWih1[gj * 256 + k] : eWhh1[gj * 256 + (k - 256)];
        else if (region == 2) {
            if (k < 256) v = dWhh0[gj * 256 + k];
            else {                               // W_eff = dWih0 . Wout
                float acc = 0.f; int kk = k - 256;
                #pragma unroll 8
                for (int f = 0; f < 32; ++f) acc += dWih0[gj * 32 + f] * Wout[f * 256 + kk];
                v = acc;
            }
        } else                v = (k < 256) ? dWih1[gj * 256 + k] : dWhh1[gj * 256 + (k - 256)];
        wsu[u] = f2bf(v);
    }
    // zero parity h buffers + flags (h1dec needs no zeroing: written before read)
    for (long z = (long)blockIdx.x * blockDim.x + threadIdx.x; z < (long)(4 * HPAR);
         z += (long)gridDim.x * blockDim.x)
        wsu[U_H0 + z] = 0;
    for (long z = (long)blockIdx.x * blockDim.x + threadIdx.x; z < 2048;
         z += (long)gridDim.x * blockDim.x)
        wsu[U_CTR + z] = 0;
}

// ---- persistent seq2seq: 256 wgs = 16 batch-groups x 16 gate-slices, MFMA + reg-B ----
__global__ __launch_bounds__(TPB) void lstm_main(
    const float* __restrict__ x,
    const float* __restrict__ eb0, const float* __restrict__ eb1,
    const float* __restrict__ db0, const float* __restrict__ db1,
    const float* __restrict__ Wout, const float* __restrict__ bout,
    const float* __restrict__ dWih0,
    float* __restrict__ ws, float* __restrict__ out)
{
    const int gi = blockIdx.x >> 4;
    const int gb = blockIdx.x & 15;   // stride-16 blocks -> same XCD per group

    unsigned short* wsu = (unsigned short*)ws;
    const unsigned short* h0u = wsu + U_H0;
    const unsigned short* h1u = wsu + U_H1;
    const unsigned short* hdu = wsu + U_HD;
    unsigned* h0d = (unsigned*)(wsu + U_H0);
    unsigned* hdd = (unsigned*)(wsu + U_HD);
    unsigned* flg = (unsigned*)(wsu + U_CTR) + gb * 32;

    const int t  = threadIdx.x;
    const int wv = t >> 6;
    const int ln = t & 63;
    const int nt = wv & 3, w2 = wv >> 2;
    const int arow = ln & 15, ak = (ln >> 4) << 3;

    __shared__ __align__(16) unsigned short Atile[16 * ASTRIDE];   // 16.25 KB
    __shared__ __align__(16) unsigned short Xtile[16 * XSTRIDE];   // 1.25 KB
    __shared__ float pbuf[2][16][68];
    __shared__ float cst[2][16][16];
    __shared__ float sb[5][64];   // eb0, eb1, b_eff, db1, db0

    if (t < 64) {
        int gj = (t >> 4) * 256 + gi * 16 + (t & 15);
        sb[0][t] = eb0[gj]; sb[1][t] = eb1[gj]; sb[3][t] = db1[gj]; sb[4][t] = db0[gj];
        float be = db0[gj];
        #pragma unroll 8
        for (int f = 0; f < 32; ++f) be += dWih0[gj * 32 + f] * bout[f];
        sb[2][t] = be;
    }
    if (t < 256) { cst[0][t >> 4][t & 15] = 0.f; cst[1][t >> 4][t & 15] = 0.f; }

    // per-wave register-resident B fragments (loop-invariant per segment)
    bf16x8 B0[8], B1[8];
    const int kbs0 = w2 ? 4 : 0, kbn0 = w2 ? 5 : 4;   // enc L0 split of KB0=9
    const int kbs1 = w2 ? 8 : 0;                       // K=512 split: 8 each
    auto loadB = [&](size_t ubase, int KB, int kbs, int kbn, bf16x8* Breg) {
        #pragma unroll
        for (int i = 0; i < 8; ++i)
            if (i < kbn)
                Breg[i] = *(const bf16x8*)(wsu + ubase +
                            ((size_t)(nt * KB + kbs + i) * 64 + ln) * 8);
    };

    int posts = 0;
    // Always entered right after a __syncthreads-terminated phase: all waves' global
    // stores are vmcnt-drained (write-through, acked at IC) before the flag store.
    auto gsync = [&]() {
        ++posts;
        if (t == 0)
            __hip_atomic_store(flg + gi, (unsigned)posts, __ATOMIC_RELAXED,
                               __HIP_MEMORY_SCOPE_AGENT);
        if (wv == 0) {
            for (;;) {
                unsigned v = __hip_atomic_load(flg + (ln & 15), __ATOMIC_RELAXED,
                                               __HIP_MEMORY_SCOPE_AGENT);
                if (__all((int)(v >= (unsigned)posts))) break;
                __builtin_amdgcn_s_sleep(1);
            }
        }
        __syncthreads();
    };

    auto stageEnc = [&](const unsigned short* h0src, const unsigned short* h1src, int xs) {
        const int r = t >> 5, c8 = t & 31;
        uint4 a, b;
        ldg_sc2(h0src + (size_t)(gb * RPG + r) * 256 + c8 * 8,
                h1src + (size_t)(gb * RPG + r) * 256 + c8 * 8, a, b);
        float xv = 0.f;
        if (xs >= 0) xv = x[((size_t)(gb * RPG + r) * TIN + xs) * FF + c8];
        *(uint4*)(Atile + r * ASTRIDE + c8 * 8) = a;
        *(uint4*)(Atile + r * ASTRIDE + 256 + c8 * 8) = b;
        if (xs >= 0) Xtile[r * XSTRIDE + c8] = f2bf(xv);
    };
    auto stageOne = [&](const unsigned short* src, int colbase) {
        const int r = t >> 5, c8 = t & 31;
        uint4 a = ldg_sc(src + (size_t)(gb * RPG + r) * 256 + c8 * 8);
        *(uint4*)(Atile + r * ASTRIDE + colbase + c8 * 8) = a;
    };
    auto stageTwo = [&](const unsigned short* s0, int cb0, const unsigned short* s1, int cb1) {
        const int r = t >> 5, c8 = t & 31;
        uint4 a, b;
        ldg_sc2(s0 + (size_t)(gb * RPG + r) * 256 + c8 * 8,
                s1 + (size_t)(gb * RPG + r) * 256 + c8 * 8, a, b);
        *(uint4*)(Atile + r * ASTRIDE + cb0 + c8 * 8) = a;
        *(uint4*)(Atile + r * ASTRIDE + cb1 + c8 * 8) = b;
    };
    auto stageZero = [&](int colbase) {
        const int r = t >> 5, c8 = t & 31;
        uint4 z = {0u, 0u, 0u, 0u};
        *(uint4*)(Atile + r * ASTRIDE + colbase + c8 * 8) = z;
    };

    // MFMA phase with register B; fused cell update + write-through h store; ends barriered
    auto phase = [&](const bf16x8* Breg, int kbs, int kbn, bool withX, const float* bias,
                     int layer, unsigned* hdstDw, bool addY0) {
        f32x4 acc = {0.f, 0.f, 0.f, 0.f};
        #pragma unroll
        for (int i = 0; i < 8; ++i) {
            if (i < kbn) {
                const int kb = kbs + i;
                bf16x8 a;
                if (withX && kb == 0) a = *(const bf16x8*)(Xtile + arow * XSTRIDE + ak);
                else {
                    const int koff = (withX ? (kb - 1) : kb) * 32;
                    a = *(const bf16x8*)(Atile + arow * ASTRIDE + koff + ak);
                }
                acc = __builtin_amdgcn_mfma_f32_16x16x32_bf16(a, Breg[i], acc, 0, 0, 0);
            }
        }
        #pragma unroll
        for (int rg = 0; rg < 4; ++rg)        // D: col=lane&15, row=(lane>>4)*4+rg
            pbuf[w2][(ln >> 4) * 4 + rg][nt * 16 + arow] = acc[rg];
        __syncthreads();
        if (t < 128) {
            const int r = t >> 3, c2 = t & 7;
            const int c0 = c2 * 2, c1 = c0 + 1;
            float xi0 = GATE(bias, 0, r, c0), xf0 = GATE(bias, 1, r, c0);
            float xg0 = GATE(bias, 2, r, c0), xo0 = GATE(bias, 3, r, c0);
            float xi1 = GATE(bias, 0, r, c1), xf1 = GATE(bias, 1, r, c1);
            float xg1 = GATE(bias, 2, r, c1), xo1 = GATE(bias, 3, r, c1);
            if (addY0) {                       // first dec step: + Wih0 * y0, y0 = x[:,-1,:]
                const float* xp = x + ((size_t)(gb * RPG + r) * TIN + (TIN - 1)) * FF;
                float xr[32];
                #pragma unroll
                for (int f = 0; f < 32; ++f) xr[f] = xp[f];
                #pragma unroll
                for (int g = 0; g < 4; ++g) {
                    const float* w0 = dWih0 + (size_t)(g * 256 + gi * 16 + c0) * 32;
                    const float* w1 = dWih0 + (size_t)(g * 256 + gi * 16 + c1) * 32;
                    float a0 = 0.f, a1 = 0.f;
                    #pragma unroll
                    for (int f = 0; f < 32; ++f) {
                        a0 = fmaf(w0[f], xr[f], a0);
                        a1 = fmaf(w1[f], xr[f], a1);
                    }
                    if (g == 0) { xi0 += a0; xi1 += a1; }
                    else if (g == 1) { xf0 += a0; xf1 += a1; }
                    else if (g == 2) { xg0 += a0; xg1 += a1; }
                    else { xo0 += a0; xo1 += a1; }
                }
            }
            float ca = cst[layer][r][c0], cb = cst[layer][r][c1];
            float cn0 = sigf(xf0) * ca + sigf(xi0) * tanhfast(xg0);
            float cn1 = sigf(xf1) * cb + sigf(xi1) * tanhfast(xg1);
            cst[layer][r][c0] = cn0; cst[layer][r][c1] = cn1;
            float h0v = sigf(xo0) * tanhfast(cn0);
            float h1v = sigf(xo1) * tanhfast(cn1);
            unsigned pv = (unsigned)f2bf(h0v) | ((unsigned)f2bf(h1v) << 16);
            __hip_atomic_store(hdstDw + (size_t)(gb * RPG + r) * 128 + gi * 8 + c2, pv,
                               __ATOMIC_RELAXED, __HIP_MEMORY_SCOPE_AGENT);
        }
        __syncthreads();
    };

    // ---- init: enc B-fragments -> regs; h0(-1)=0; Xtile = x(0) ----
    loadB(U_E0 + (size_t)gi * 18432, KB0, kbs0, kbn0, B0);
    loadB(U_E1 + (size_t)gi * 32768, KB1, kbs1, 8,    B1);
    { const int r = t >> 5, c8 = t & 31;
      uint4 z = {0u, 0u, 0u, 0u};
      *(uint4*)(Atile + r * ASTRIDE + c8 * 8) = z;
      Xtile[r * XSTRIDE + c8] = f2bf(x[((size_t)(gb * RPG + r) * TIN) * FF + c8]); }
    __syncthreads();

    // ---- encoder: 1 gsync/step ----
    for (int s = 0; s < TIN; ++s) {
        const int rp = s & 1, wp = rp ^ 1;
        phase(B0, kbs0, kbn0, true, sb[0], 0, h0d + (size_t)wp * (HPAR / 2), false);
        gsync();                                   // publishes h0(s) (+ h1(s-1) earlier)
        stageEnc(h0u + (size_t)wp * HPAR, h1u + (size_t)rp * HPAR,
                 (s + 1 < TIN) ? s + 1 : -1);
        __syncthreads();
        phase(B1, kbs1, 8, false, sb[1], 1,
              (unsigned*)(wsu + U_H1) + (size_t)wp * (HPAR / 2), false);
    }

    // ---- decoder B-fragments -> regs (enc phases complete for this wave) ----
    loadB(U_D0 + (size_t)gi * 32768, KB1, kbs1, 8, B0);
    loadB(U_D1 + (size_t)gi * 32768, KB1, kbs1, 8, B1);

    // ---- decoder: 2 gsyncs/step; h0(s-1) persists in Atile cols 0..255 ----
    for (int s = TIN; s < TIN + TOUT; ++s) {
        const int wp = (s & 1) ^ 1, td = s - TIN;
        gsync();                                   // publishes h1(s-1)
        if (td == 0) stageZero(256);               // W_eff·0: y0 handled via addY0
        else stageOne(hdu + (size_t)(td - 1) * HPAR, 256);
        __syncthreads();
        phase(B0, kbs1, 8, false, (td == 0) ? sb[4] : sb[2], 0,
              h0d + (size_t)wp * (HPAR / 2), td == 0);
        gsync();                                   // publishes h0(s)
        if (td == 0) stageTwo(h0u + (size_t)wp * HPAR, 0, h1u + 0 * HPAR, 256);
        else stageOne(h0u + (size_t)wp * HPAR, 0);
        __syncthreads();
        phase(B1, kbs1, 8, false, sb[3], 1, hdd + (size_t)td * (HPAR / 2), false);
    }

    // ---- final sync: all h1dec published ----
    gsync();

    // ---- deferred y pass: out[r][td][f] for r in gb rows, f = 2gi+{0,1}; no barriers ----
    {
        const int r = t >> 5, fq = (t >> 4) & 1, kc = t & 15;
        const int f = gi * 2 + fq;
        const float* wf = Wout + (size_t)f * 256 + kc * 16;
        float wreg[16];
        #pragma unroll
        for (int i = 0; i < 16; ++i) wreg[i] = wf[i];
        const float bo = bout[f];
        for (int td = 0; td < TOUT; ++td) {
            const unsigned short* hp = hdu + (size_t)td * HPAR +
                                       (size_t)(gb * RPG + r) * 256 + kc * 16;
            uint4 ua = *(const uint4*)hp;
            uint4 ub = *(const uint4*)(hp + 8);
            unsigned w[8] = {ua.x, ua.y, ua.z, ua.w, ub.x, ub.y, ub.z, ub.w};
            float a = 0.f;
            #pragma unroll
            for (int j = 0; j < 8; ++j) {
                a = fmaf(__uint_as_float(w[j] << 16),        wreg[2 * j],     a);
                a = fmaf(__uint_as_float(w[j] & 0xffff0000u), wreg[2 * j + 1], a);
            }
            #pragma unroll
            for (int off = 1; off < 16; off <<= 1) a += __shfl_xor(a, off, 64);
            if (kc == 0)
                out[((size_t)(gb * RPG + r) * TOUT + td) * FF + f] = a + bo;
        }
    }
}

extern "C" void kernel_launch(void* const* d_in, const int* in_sizes, int n_in,
                              void* d_out, int out_size, void* d_ws, size_t ws_size,
                              hipStream_t stream) {
    const float* x     = (const float*)d_in[0];
    const float* eWih0 = (const float*)d_in[1];
    const float* eWhh0 = (const float*)d_in[2];
    const float* eb0   = (const float*)d_in[3];
    const float* eWih1 = (const float*)d_in[4];
    const float* eWhh1 = (const float*)d_in[5];
    const float* eb1   = (const float*)d_in[6];
    const float* dWih0 = (const float*)d_in[7];
    const float* dWhh0 = (const float*)d_in[8];
    const float* db0   = (const float*)d_in[9];
    const float* dWih1 = (const float*)d_in[10];
    const float* dWhh1 = (const float*)d_in[11];
    const float* db1   = (const float*)d_in[12];
    const float* dWout = (const float*)d_in[13];
    const float* dbout = (const float*)d_in[14];
    float* ws = (float*)d_ws;
    float* out = (float*)d_out;

    prep_kernel<<<1024, 256, 0, stream>>>(eWih0, eWhh0, eWih1, eWhh1,
                                          dWih0, dWhh0, dWih1, dWhh1, dWout, ws);
    lstm_main<<<NGS * NBG, TPB, 0, stream>>>(x, eb0, eb1, db0, db1,
                                             dWout, dbout, dWih0, ws, out);
}